// Round 1
// 285.015 us; speedup vs baseline: 1.0662x; 1.0662x over previous
//
#include <hip/hip_runtime.h>
#include <stdint.h>

// out[b,t,n,d] = (sqrt(t+1)/512) * sum_k ( sr[b,t,d,k]*cos(2*pi*n*k/512)
//                                        - si[b,t,d,k]*sin(2*pi*n*k/512) )
// B=4, T=512, N=512 (seq), D=64, K=32.
//
// GEMM form per (b,t):  out[n,d] = sum_{kk=0..63} T[n,kk] * S[d,kk]
//   T[n,2k]   = cos(2*pi*n*k/512)      (bf16 table in d_ws, built per call)
//   T[n,2k+1] = sin(2*pi*n*k/512)
//   S[d,2k]   =  sr * sqrt(t+1)/512    (bf16, staged to LDS)
//   S[d,2k+1] = -si * sqrt(t+1)/512
// MFMA 16x16x32 bf16: A[m=lane&15][k=quad*8+j]; B[k=quad*8+j][n=lane&15];
// D: col = lane&15, row = quad*4 + reg.  (doc-verified layouts, m89/m118/m120)
//
// v2 changes vs v1 (304 us):
//  - epilogue: accumulator tiles bounce through wave-private LDS (stride 68,
//    2-way bank aliasing only = free) and store as 1KB-contiguous nontemporal
//    dwordx4 instead of 128 scalar dword stores in 64B segments.
//  - A-fragments (twiddle rows, L2-resident) loaded per-i with 1-step
//    prefetch instead of held in 64 VGPRs; __launch_bounds__(256,4).

typedef short bf16x8 __attribute__((ext_vector_type(8)));
typedef float f32x4  __attribute__((ext_vector_type(4)));

__device__ __forceinline__ unsigned short f2bf(float f) {
    union { float f; uint32_t u; } v; v.f = f;
    uint32_t u = v.u;
    u += 0x7fffu + ((u >> 16) & 1u);   // round-to-nearest-even
    return (unsigned short)(u >> 16);
}

// d_ws table: T[n][kk], n in [0,512), kk in [0,64), bf16 bits. 64 KB.
__global__ void build_twiddle(unsigned short* __restrict__ T) {
    int gid = blockIdx.x * blockDim.x + threadIdx.x;   // 0..32767
    int n   = gid >> 6;
    int kk  = gid & 63;
    int k   = kk >> 1;
    int m   = (n * k) & 511;                            // exact 2*pi periodic reduction
    float ang = (float)m * (6.283185307179586f / 512.0f);
    float val = (kk & 1) ? sinf(ang) : cosf(ang);
    T[gid] = f2bf(val);
}

__global__ __launch_bounds__(256, 4) void cum_ifft(
    const float* __restrict__ spectral,
    const unsigned short* __restrict__ T,
    float* __restrict__ out)
{
    __shared__ unsigned short S[64 * 72];     // [d][kk] bf16, rows padded 64->72
    __shared__ float XP[4][16 * 68];          // per-wave transpose buffer, stride 68
    const int bt  = blockIdx.x;               // 0..2047  (b*512 + t)
    const int tid = threadIdx.x;
    const int t   = bt & 511;
    const float scale = sqrtf((float)(t + 1)) * (1.0f / 512.0f);

    // ---- stage spectral[b,t,:,:,:] (4096 floats = 1024 float4) into LDS as bf16
    const float4* src = (const float4*)(spectral + (size_t)bt * 4096);
    #pragma unroll
    for (int it = 0; it < 4; ++it) {
        int idx = it * 256 + tid;          // 0..1023
        int d   = idx >> 4;                // 0..63
        int k2  = idx & 15;                // k pair: k = 2*k2, 2*k2+1
        float4 v = src[idx];               // sr(k0), si(k0), sr(k1), si(k1)
        unsigned int w0 = (unsigned int)f2bf(v.x * scale) |
                          ((unsigned int)f2bf(-v.y * scale) << 16);
        unsigned int w1 = (unsigned int)f2bf(v.z * scale) |
                          ((unsigned int)f2bf(-v.w * scale) << 16);
        uint2* dst = (uint2*)(&S[d * 72 + k2 * 4]);
        *dst = make_uint2(w0, w1);         // single ds_write_b64
    }
    __syncthreads();

    const int lane = tid & 63;
    const int w    = tid >> 6;             // wave 0..3
    const int lrow = lane & 15;
    const int quad = lane >> 4;

    // ---- B fragments: lane holds S[d = dt*16+lrow][kk = ks*32 + quad*8 + j]
    bf16x8 bfrag[4][2];
    #pragma unroll
    for (int dt = 0; dt < 4; ++dt)
        #pragma unroll
        for (int ks = 0; ks < 2; ++ks)
            bfrag[dt][ks] = *(const bf16x8*)(&S[(dt * 16 + lrow) * 72 + ks * 32 + quad * 8]);

    float* outp = out + (size_t)bt * (512 * 64);
    float* xp   = &XP[w][0];

    // ---- A fragments loaded per-i (T is 64KB, L2-resident), 1-step prefetch.
    // lane holds T[n = (w*8+i)*16 + lrow][kk = ks*32 + quad*8 + j]
    int n0 = (w * 8) * 16;
    bf16x8 a0 = *(const bf16x8*)(&T[(n0 + lrow) * 64 + quad * 8]);
    bf16x8 a1 = *(const bf16x8*)(&T[(n0 + lrow) * 64 + 32 + quad * 8]);

    for (int i = 0; i < 8; ++i) {
        bf16x8 na0, na1;
        if (i < 7) {
            int nn = (w * 8 + i + 1) * 16 + lrow;
            na0 = *(const bf16x8*)(&T[nn * 64 + quad * 8]);
            na1 = *(const bf16x8*)(&T[nn * 64 + 32 + quad * 8]);
        }

        f32x4 acc0 = {0.f, 0.f, 0.f, 0.f};
        f32x4 acc1 = {0.f, 0.f, 0.f, 0.f};
        f32x4 acc2 = {0.f, 0.f, 0.f, 0.f};
        f32x4 acc3 = {0.f, 0.f, 0.f, 0.f};
        acc0 = __builtin_amdgcn_mfma_f32_16x16x32_bf16(a0, bfrag[0][0], acc0, 0, 0, 0);
        acc1 = __builtin_amdgcn_mfma_f32_16x16x32_bf16(a0, bfrag[1][0], acc1, 0, 0, 0);
        acc2 = __builtin_amdgcn_mfma_f32_16x16x32_bf16(a0, bfrag[2][0], acc2, 0, 0, 0);
        acc3 = __builtin_amdgcn_mfma_f32_16x16x32_bf16(a0, bfrag[3][0], acc3, 0, 0, 0);
        acc0 = __builtin_amdgcn_mfma_f32_16x16x32_bf16(a1, bfrag[0][1], acc0, 0, 0, 0);
        acc1 = __builtin_amdgcn_mfma_f32_16x16x32_bf16(a1, bfrag[1][1], acc1, 0, 0, 0);
        acc2 = __builtin_amdgcn_mfma_f32_16x16x32_bf16(a1, bfrag[2][1], acc2, 0, 0, 0);
        acc3 = __builtin_amdgcn_mfma_f32_16x16x32_bf16(a1, bfrag[3][1], acc3, 0, 0, 0);

        // ---- transpose 16x64 tile through wave-private LDS.
        // write: row = quad*4 + r, col = dt*16 + lrow, stride 68.
        // bank = (4*row + 16*dt + lrow) % 32 -> 2-way aliasing only (free).
        #pragma unroll
        for (int r = 0; r < 4; ++r) {
            xp[(quad * 4 + r) * 68 +  0 + lrow] = acc0[r];
            xp[(quad * 4 + r) * 68 + 16 + lrow] = acc1[r];
            xp[(quad * 4 + r) * 68 + 32 + lrow] = acc2[r];
            xp[(quad * 4 + r) * 68 + 48 + lrow] = acc3[r];
        }
        // wave-private buffer: order write->read at compile time and drain LDS.
        asm volatile("s_waitcnt lgkmcnt(0)" ::: "memory");

        // read back float4-per-lane, store 1KB contiguous per instruction:
        // lane l -> row 4*j + (l>>4), bytes (l&15)*16 .. +15 of that row.
        int nrow = (w * 8 + i) * 16;
        #pragma unroll
        for (int j = 0; j < 4; ++j) {
            int row = j * 4 + quad;
            f32x4 v = *(const f32x4*)(&xp[row * 68 + lrow * 4]);
            __builtin_nontemporal_store(
                v, (f32x4*)(outp + (size_t)(nrow + row) * 64 + lrow * 4));
        }
        // prevent next iteration's LDS writes from moving above these reads
        asm volatile("" ::: "memory");

        a0 = na0; a1 = na1;
    }
}

extern "C" void kernel_launch(void* const* d_in, const int* in_sizes, int n_in,
                              void* d_out, int out_size, void* d_ws, size_t ws_size,
                              hipStream_t stream) {
    const float* spectral = (const float*)d_in[0];
    unsigned short* T     = (unsigned short*)d_ws;   // 64 KB twiddle table
    float* out            = (float*)d_out;

    build_twiddle<<<128, 256, 0, stream>>>(T);
    cum_ifft<<<2048, 256, 0, stream>>>(spectral, T, out);
}